// Round 13
// baseline (533.065 us; speedup 1.0000x reference)
//
#include <hip/hip_runtime.h>
#include <math.h>

#define NROWS 16384
#define DIM   512
#define NPROTO 4096
#define TINV (1.0f / 0.9f)
#define LOSS_OFF ((size_t)NROWS * DIM)
#define IDX_OFF  ((size_t)NROWS * DIM + 1)
#define LCAP 160
#define LTHR 10.0f

typedef __attribute__((ext_vector_type(4))) int i32x4;

__global__ void zero_loss_kernel(float* out) { out[LOSS_OFF] = 0.0f; }

static __device__ __forceinline__ void gl_lds16(const void* g, void* l) {
    __builtin_amdgcn_global_load_lds((const __attribute__((address_space(1))) unsigned int*)g,
                                     (__attribute__((address_space(3))) unsigned int*)l, 16, 0, 0);
}
#define WAIT_VM0() asm volatile("s_waitcnt vmcnt(0)" ::: "memory")
#define SBAR() __builtin_amdgcn_sched_barrier(0)

// ---------------- pre-split: fp32 -> 2x int8 limbs (x ~= s*(128*q1+q0)) ----------------
// output plane layout: [g32 0..15][row][32 bytes]  (g32 covers k = g32*32 .. +32)
__global__ __launch_bounds__(256)
void split_i8_kernel(const float* __restrict__ src, char* __restrict__ d1, char* __restrict__ d0,
                     float* __restrict__ dScale, int nrows)
{
    __shared__ __align__(16) char s1[32][512];
    __shared__ __align__(16) char s0[32][512];
    const int tid = threadIdx.x;
    const int row = tid >> 3;            // 0..31
    const int sub = tid & 7;             // 0..7 (64 elems each)
    const int r0 = blockIdx.x * 32;
    const float* rp = &src[(size_t)(r0 + row) * DIM + sub * 64];
    float v[64];
    float mx = 1e-20f;
#pragma unroll
    for (int i = 0; i < 16; ++i) {
        float4 f = *(const float4*)&rp[i * 4];
        v[i*4+0] = f.x; v[i*4+1] = f.y; v[i*4+2] = f.z; v[i*4+3] = f.w;
        mx = fmaxf(mx, fmaxf(fmaxf(fabsf(f.x), fabsf(f.y)), fmaxf(fabsf(f.z), fabsf(f.w))));
    }
#pragma unroll
    for (int off = 1; off < 8; off <<= 1) mx = fmaxf(mx, __shfl_xor(mx, off));
    const float s   = mx * (1.0f / 16256.0f);    // 16256 = 127*128
    const float inv = 16256.0f / mx;
    if (sub == 0) dScale[r0 + row] = s;
#pragma unroll
    for (int i = 0; i < 64; ++i) {
        float q  = v[i] * inv;
        float a1 = rintf(q * (1.0f / 128.0f));
        float a0 = rintf(q - 128.0f * a1);
        s1[row][sub * 64 + i] = (char)(int)a1;
        s0[row][sub * 64 + i] = (char)(int)a0;
    }
    __syncthreads();
    // write [g32][row][32]: 16 g32 x 32 rows = 512 tiles per limb, 2 per thread
#pragma unroll
    for (int i = 0; i < 2; ++i) {
        int idx = i * 256 + tid;
        int g = idx >> 5;
        int rr = idx & 31;
        size_t o = ((size_t)g * nrows + r0 + rr) * 32;
        *(ulonglong2*)&d1[o]      = *(const ulonglong2*)&s1[rr][g * 32];
        *(ulonglong2*)&d1[o + 16] = *(const ulonglong2*)&s1[rr][g * 32 + 16];
        *(ulonglong2*)&d0[o]      = *(const ulonglong2*)&s0[rr][g * 32];
        *(ulonglong2*)&d0[o + 16] = *(const ulonglong2*)&s0[rr][g * 32 + 16];
    }
}

// ======== wave-autonomous i8 GEMM (single buf, vmcnt(0) per step) + collect + epilogue ========
#define BM 32
#define BN 256
#define NCHUNK (NPROTO / BN)        // 16
#define NT 8                        // BK=64 -> 8 t-steps per chunk

__global__ __launch_bounds__(256, 2)
void attr_proto_wa2(const float* __restrict__ A, const float* __restrict__ Pr,
                    const float* __restrict__ U, float* __restrict__ out,
                    uint2* __restrict__ gList,
                    const char* __restrict__ wsA1, const char* __restrict__ wsA0,
                    const char* __restrict__ wsP1, const char* __restrict__ wsP0,
                    const float* __restrict__ wsSA, const float* __restrict__ wsSP)
{
    __shared__ __align__(16) char aL[2][16][32][32];     // 32 KB [limb][g32][row][32B] resident
    __shared__ __align__(16) char pL[4][2][2][64][32];   // 32 KB [wave][limb][g2l][proto][32B] single buf
    __shared__ int cnt[BM];

    const int tid = threadIdx.x;
    const int w = tid >> 6;
    const int lane = tid & 63;
    const int l4 = lane & 15;
    const int lh = lane >> 4;
    const int row0 = blockIdx.x * BM;

    if (tid < BM) cnt[tid] = 0;

    // ---- P stage: 8 slots/wave (limb, g2l, half); each gl_lds16 = 32 protos x 32B = 1KB
    const char* gpP[8];
    char* ldP[8];
#pragma unroll
    for (int si = 0; si < 8; ++si) {
        int limb = si >> 2, g2l = (si >> 1) & 1, half = si & 1;
        gpP[si] = (limb ? wsP0 : wsP1)
                + ((size_t)g2l * NPROTO + w * 64 + half * 32 + (lane >> 1)) * 32 + (lane & 1) * 16;
        ldP[si] = &pL[w][limb][g2l][half * 32][0] + (size_t)lane * 16;
    }
    const int strP = 2 * NPROTO * 32;                 // t -> t+1 (g32 += 2)
    const int fxP  = -16 * NPROTO * 32 + BN * 32;     // g32 -= 16, pbase += BN
#define STAGE_P() { _Pragma("unroll") for (int si = 0; si < 8; ++si) { \
        gl_lds16(gpP[si], ldP[si]); gpP[si] += strP; } }
#define FIXUP_P() { _Pragma("unroll") for (int si = 0; si < 8; ++si) gpP[si] += fxP; }

    // ---- prologue: resident A (8 slots/wave: 32 total = 2 limb x 16 g32)
#pragma unroll
    for (int q = 0; q < 8; ++q) {
        int s = w * 8 + q;                   // 0..31
        int limb = s >> 4, g2 = s & 15;
        const char* base = limb ? wsA0 : wsA1;
        gl_lds16(base + ((size_t)g2 * NROWS + row0 + (lane >> 1)) * 32 + (lane & 1) * 16,
                 &aL[limb][g2][0][0] + (size_t)lane * 16);
    }
    __syncthreads();     // ONLY barrier before epilogue: A ready (vmcnt(0) drained), cnt init visible

    // per-thread row scales + wave-local running max (this thread's 8 rows)
    float sav[8], mloc[8];
#pragma unroll
    for (int mf = 0; mf < 2; ++mf)
#pragma unroll
        for (int r = 0; r < 4; ++r) {
            sav[mf * 4 + r]  = wsSA[row0 + mf * 16 + lh * 4 + r];
            mloc[mf * 4 + r] = -1e30f;
        }

    i32x4 c11[2][4], c10[2][4], c01[2][4];

#define COMPUTE(T) { \
    const int g2a = (T) * 2 + (lh >> 1); \
    const int gsub = (lh & 1) * 16; \
    i32x4 a1[2], a0[2], b1[4], b0[4]; \
    _Pragma("unroll") for (int mf = 0; mf < 2; ++mf) { \
        a1[mf] = *(const i32x4*)&aL[0][g2a][mf * 16 + l4][gsub]; \
        a0[mf] = *(const i32x4*)&aL[1][g2a][mf * 16 + l4][gsub]; } \
    _Pragma("unroll") for (int nf = 0; nf < 4; ++nf) { \
        b1[nf] = *(const i32x4*)&pL[w][0][lh >> 1][nf * 16 + l4][gsub]; \
        b0[nf] = *(const i32x4*)&pL[w][1][lh >> 1][nf * 16 + l4][gsub]; } \
    _Pragma("unroll") for (int mf = 0; mf < 2; ++mf) \
    _Pragma("unroll") for (int nf = 0; nf < 4; ++nf) { \
        c11[mf][nf] = __builtin_amdgcn_mfma_i32_16x16x64_i8(a1[mf], b1[nf], c11[mf][nf], 0, 0, 0); \
        c10[mf][nf] = __builtin_amdgcn_mfma_i32_16x16x64_i8(a1[mf], b0[nf], c10[mf][nf], 0, 0, 0); \
        c01[mf][nf] = __builtin_amdgcn_mfma_i32_16x16x64_i8(a0[mf], b1[nf], c01[mf][nf], 0, 0, 0); } }

    for (int ch = 0; ch < NCHUNK; ++ch) {
        const int pbase = ch * BN;
        float spv[4];
#pragma unroll
        for (int nf = 0; nf < 4; ++nf) spv[nf] = wsSP[pbase + w * 64 + nf * 16 + l4];
#pragma unroll
        for (int mf = 0; mf < 2; ++mf)
#pragma unroll
            for (int nf = 0; nf < 4; ++nf) {
                c11[mf][nf] = i32x4{0,0,0,0}; c10[mf][nf] = i32x4{0,0,0,0}; c01[mf][nf] = i32x4{0,0,0,0};
            }

        for (int t = 0; t < NT; ++t) {
            SBAR();                 // pin prior step's ds_reads above the overwrite
            STAGE_P();              // stage tile t into this wave's private buffer
            WAIT_VM0();             // ALL outstanding VMEM drained (spill-proof, prefetch-free)
            SBAR();                 // nothing below may hoist above the wait
            COMPUTE(t);
        }
        FIXUP_P();

        // ---- combine limbs + gumbel + wave-local collect (NO barriers)
        // D layout: row=(lane>>4)*4+reg, col=lane&15
#pragma unroll
        for (int mf = 0; mf < 2; ++mf) {
            float zf[4][4];
            const int rb = row0 + mf * 16 + lh * 4;
#pragma unroll
            for (int nf = 0; nf < 4; ++nf)
#pragma unroll
                for (int r = 0; r < 4; ++r) {
                    float dist = sav[mf * 4 + r] * spv[nf] *
                                 (16384.0f * (float)c11[mf][nf][r] +
                                  128.0f * ((float)c10[mf][nf][r] + (float)c01[mf][nf][r]));
                    float u = U[(size_t)(rb + r) * NPROTO + pbase + w * 64 + nf * 16 + l4];
                    float g = -__logf(-__logf(u + 1e-10f) + 1e-10f);
                    zf[nf][r] = (dist + g) * TINV;
                }
            float rm[4];
#pragma unroll
            for (int r = 0; r < 4; ++r)
                rm[r] = fmaxf(fmaxf(zf[0][r], zf[1][r]), fmaxf(zf[2][r], zf[3][r]));
#pragma unroll
            for (int off = 1; off < 16; off <<= 1)
#pragma unroll
                for (int r = 0; r < 4; ++r) rm[r] = fmaxf(rm[r], __shfl_xor(rm[r], off));
#pragma unroll
            for (int r = 0; r < 4; ++r) {
                const int rl = mf * 16 + lh * 4 + r;
                float mcur = fmaxf(mloc[mf * 4 + r], rm[r]);
                mloc[mf * 4 + r] = mcur;
                float thrv = mcur - LTHR;   // wave-local (<= final max): conservative, extra inserts only
#pragma unroll
                for (int nf = 0; nf < 4; ++nf) {
                    float z = zf[nf][r];
                    if (z > thrv) {
                        int pos = atomicAdd(&cnt[rl], 1);
                        if (pos < LCAP) {
                            uint2 en; en.x = __float_as_uint(z);
                            en.y = (unsigned)(pbase + w * 64 + nf * 16 + l4);
                            gList[(size_t)(row0 + rl) * LCAP + pos] = en;
                        }
                    }
                }
            }
        }
    }
#undef STAGE_P
#undef FIXUP_P
#undef COMPUTE

    // ================= fused epilogue (r11 verbatim; true M/L from list) =================
    __syncthreads();               // cnt + gList stores visible block-wide
    float lossTot = 0.f;
    for (int r = w; r < BM; r += 4) {
        const int row = row0 + r;
        const int c = min(cnt[r], LCAP);
        const uint2* lst = &gList[(size_t)row * LCAP];

        // pass 1: true max M over list
        float M = -1e30f;
        for (int e = lane; e < c; e += 64) M = fmaxf(M, __uint_as_float(lst[e].x));
#pragma unroll
        for (int off = 1; off < 64; off <<= 1) M = fmaxf(M, __shfl_xor(M, off));
        const float cutoff = M - LTHR;

        // pass 2: denominator L + approx argmax
        float L = 0.f, bz = -1e30f; int bi = 1 << 30;
        for (int e = lane; e < c; e += 64) {
            float z = __uint_as_float(lst[e].x); int p = (int)lst[e].y;
            if (z > cutoff) {
                L += __expf(z - M);
                if (z > bz || (z == bz && p < bi)) { bz = z; bi = p; }
            }
        }
#pragma unroll
        for (int off = 1; off < 64; off <<= 1) {
            L += __shfl_xor(L, off);
            float oz = __shfl_xor(bz, off); int oi = __shfl_xor(bi, off);
            if (oz > bz || (oz == bz && oi < bi)) { bz = oz; bi = oi; }
        }

        // exact argmax: r1-replica serial fp32 recompute among near-ties
        float bestz = -1e30f; int bestp = 1 << 30;
        const float* ap = &A[(size_t)row * DIM];
        for (int e = lane; e < c; e += 64) {
            float z = __uint_as_float(lst[e].x);
            if (z > bz - 3.0f) {
                int p = (int)lst[e].y;
                const float* pp = &Pr[(size_t)p * DIM];
                float d = 0.f;
                for (int k = 0; k < DIM; k += 4) {           // serial k order == r1's accumulation
                    float4 av = *(const float4*)&ap[k];
                    float4 pv = *(const float4*)&pp[k];
                    d = fmaf(av.x, pv.x, d);
                    d = fmaf(av.y, pv.y, d);
                    d = fmaf(av.z, pv.z, d);
                    d = fmaf(av.w, pv.w, d);
                }
                float u = U[(size_t)row * NPROTO + p];
                float g = -logf(-logf(u + 1e-10f) + 1e-10f); // accurate logf, as r1
                float zz = (d + g) * (1.0f / 0.9f);
                if (zz > bestz || (zz == bestz && p < bestp)) { bestz = zz; bestp = p; }
            }
        }
#pragma unroll
        for (int off = 1; off < 64; off <<= 1) {
            float oz = __shfl_xor(bestz, off); int oi = __shfl_xor(bestp, off);
            if (oz > bestz || (oz == bestz && oi < bestp)) { bestz = oz; bestp = oi; }
        }
        if (lane == 0) out[IDX_OFF + row] = (float)bestp;

        // PV gather + output + loss
        float o[8];
#pragma unroll
        for (int q = 0; q < 8; ++q) o[q] = 0.f;
        const float Li = 1.0f / L;
        for (int e = 0; e < c; ++e) {
            uint2 en = lst[e];
            float z = __uint_as_float(en.x);
            if (z > cutoff) {
                float wgt = __expf(z - M) * Li;
                const float* pp = &Pr[(size_t)en.y * DIM + lane * 8];
                float4 p0 = *(const float4*)pp;
                float4 p1 = *(const float4*)(pp + 4);
                o[0] += wgt * p0.x; o[1] += wgt * p0.y; o[2] += wgt * p0.z; o[3] += wgt * p0.w;
                o[4] += wgt * p1.x; o[5] += wgt * p1.y; o[6] += wgt * p1.z; o[7] += wgt * p1.w;
            }
        }
        const float* fr = &A[(size_t)row * DIM + lane * 8];
        float4 f0 = *(const float4*)fr; float4 f1 = *(const float4*)(fr + 4);
        *(float4*)&out[(size_t)row * DIM + lane * 8]     = make_float4(o[0], o[1], o[2], o[3]);
        *(float4*)&out[(size_t)row * DIM + lane * 8 + 4] = make_float4(o[4], o[5], o[6], o[7]);
        lossTot += fabsf(o[0]-f0.x) + fabsf(o[1]-f0.y) + fabsf(o[2]-f0.z) + fabsf(o[3]-f0.w)
                 + fabsf(o[4]-f1.x) + fabsf(o[5]-f1.y) + fabsf(o[6]-f1.z) + fabsf(o[7]-f1.w);
    }
#pragma unroll
    for (int off = 1; off < 64; off <<= 1) lossTot += __shfl_xor(lossTot, off);
    if (lane == 0) atomicAdd(&out[LOSS_OFF], lossTot * (1.0f / ((float)NROWS * (float)DIM)));
}

// ---------------- fallback: r1 fp32 VALU kernel (no workspace needed) ----------------
#define FCAP 192
#define FTHR 20.0f

__global__ __launch_bounds__(256, 1)
void attr_proto_fused_valu(const float* __restrict__ A, const float* __restrict__ Pr,
                           const float* __restrict__ U, float* __restrict__ out)
{
    __shared__ __align__(16) float As[64][64 + 4];
    __shared__ __align__(16) float Bs[128][64 + 4];
    __shared__ float hZ[64][FCAP];
    __shared__ unsigned short hI[64][FCAP];
    __shared__ int cnt[64];
    __shared__ float mArr[64];
    __shared__ float lArr[64];
    __shared__ int pruneFlag;

    const int tid = threadIdx.x;
    const int tx = tid & 31;
    const int ty = tid >> 5;
    const int row0 = blockIdx.x * 64;

    for (int r = tid; r < 64; r += 256) cnt[r] = 0;
    if (tid == 0) pruneFlag = 0;

    float m[8], l[8], bz[8];
    int bi[8];
#pragma unroll
    for (int i = 0; i < 8; ++i) { m[i] = -INFINITY; l[i] = 0.0f; bz[i] = -INFINITY; bi[i] = 0; }
    __syncthreads();

    for (int ch = 0; ch < 32; ++ch) {
        const int pbase = ch * 128;
        float acc[8][4];
#pragma unroll
        for (int i = 0; i < 8; ++i)
#pragma unroll
            for (int j = 0; j < 4; ++j) acc[i][j] = 0.0f;

        for (int kk = 0; kk < DIM; kk += 64) {
#pragma unroll
            for (int q = 0; q < 4; ++q) {
                int lin = tid + q * 256;
                int lr = lin >> 4; int kq = (lin & 15) << 2;
                *(float4*)&As[lr][kq] = *(const float4*)&A[(size_t)(row0 + lr) * DIM + kk + kq];
            }
#pragma unroll
            for (int q = 0; q < 8; ++q) {
                int lin = tid + q * 256;
                int pr = lin >> 4; int kq = (lin & 15) << 2;
                *(float4*)&Bs[pr][kq] = *(const float4*)&Pr[(size_t)(pbase + pr) * DIM + kk + kq];
            }
            __syncthreads();
#pragma unroll 4
            for (int k4 = 0; k4 < 64; k4 += 4) {
                float4 av[8], bv[4];
#pragma unroll
                for (int i = 0; i < 8; ++i) av[i] = *(const float4*)&As[ty * 8 + i][k4];
#pragma unroll
                for (int j = 0; j < 4; ++j) bv[j] = *(const float4*)&Bs[tx + 32 * j][k4];
#pragma unroll
                for (int i = 0; i < 8; ++i)
#pragma unroll
                    for (int j = 0; j < 4; ++j) {
                        acc[i][j] += av[i].x * bv[j].x; acc[i][j] += av[i].y * bv[j].y;
                        acc[i][j] += av[i].z * bv[j].z; acc[i][j] += av[i].w * bv[j].w;
                    }
            }
            __syncthreads();
        }
#pragma unroll
        for (int i = 0; i < 8; ++i) {
            const int ri = ty * 8 + i;
            const size_t urow = (size_t)(row0 + ri) * NPROTO + pbase;
            float z[4]; float lmax = -INFINITY;
#pragma unroll
            for (int j = 0; j < 4; ++j) {
                float u = U[urow + tx + 32 * j];
                float g = -logf(-logf(u + 1e-10f) + 1e-10f);
                z[j] = (acc[i][j] + g) * TINV;
                lmax = fmaxf(lmax, z[j]);
            }
#pragma unroll
            for (int off = 16; off; off >>= 1) lmax = fmaxf(lmax, __shfl_xor(lmax, off, 32));
            const float mn = fmaxf(m[i], lmax);
            float s = 0.0f;
#pragma unroll
            for (int j = 0; j < 4; ++j) s += expf(z[j] - mn);
#pragma unroll
            for (int off = 16; off; off >>= 1) s += __shfl_xor(s, off, 32);
            l[i] = l[i] * expf(m[i] - mn) + s;
            m[i] = mn;
#pragma unroll
            for (int j = 0; j < 4; ++j) {
                const int p = pbase + tx + 32 * j;
                if (z[j] > bz[i]) { bz[i] = z[j]; bi[i] = p; }
                if (z[j] > mn - FTHR) {
                    int pos = atomicAdd(&cnt[ri], 1);
                    if (pos < FCAP) { hZ[ri][pos] = z[j]; hI[ri][pos] = (unsigned short)p; }
                }
            }
            if (tx == 0) {
                mArr[ri] = mn;
                if (cnt[ri] > 64) atomicOr(&pruneFlag, 1);
            }
        }
        __syncthreads();
        if (pruneFlag) {
            for (int r = 0; r < 64; ++r) {
                const int c0 = min(cnt[r], FCAP);
                if (c0 > 64) {
                    const float thr = mArr[r] - FTHR;
                    float ez = 0.0f; int ei = 0; bool keep = false;
                    if (tid < c0) { ez = hZ[r][tid]; ei = hI[r][tid]; keep = (ez > thr); }
                    __syncthreads();
                    if (tid == 0) cnt[r] = 0;
                    __syncthreads();
                    if (keep) { int pos = atomicAdd(&cnt[r], 1); hZ[r][pos] = ez; hI[r][pos] = (unsigned short)ei; }
                    __syncthreads();
                }
            }
            if (tid == 0) pruneFlag = 0;
            __syncthreads();
        }
    }
#pragma unroll
    for (int i = 0; i < 8; ++i) {
        const int ri = ty * 8 + i;
        float vz = bz[i]; int vi = bi[i];
#pragma unroll
        for (int off = 16; off; off >>= 1) {
            float oz = __shfl_xor(vz, off, 32); int oi = __shfl_xor(vi, off, 32);
            if (oz > vz || (oz == vz && oi < vi)) { vz = oz; vi = oi; }
        }
        if (tx == 0) { lArr[ri] = l[i]; out[IDX_OFF + row0 + ri] = (float)vi; }
    }
    __syncthreads();

    const int wv = tid >> 6;
    const int lane = tid & 63;
    float lossAcc = 0.0f;
    for (int r = wv; r < 64; r += 4) {
        const int grow = row0 + r;
        const int c = min(cnt[r], FCAP);
        const float mm = mArr[r];
        const float li = 1.0f / lArr[r];
        float o[8];
#pragma unroll
        for (int q = 0; q < 8; ++q) o[q] = 0.0f;
        for (int e = 0; e < c; ++e) {
            const float wg = expf(hZ[r][e] - mm) * li;
            const float* pp = &Pr[(size_t)hI[r][e] * DIM + lane * 8];
            float4 p0 = *(const float4*)pp; float4 p1 = *(const float4*)(pp + 4);
            o[0] += wg * p0.x; o[1] += wg * p0.y; o[2] += wg * p0.z; o[3] += wg * p0.w;
            o[4] += wg * p1.x; o[5] += wg * p1.y; o[6] += wg * p1.z; o[7] += wg * p1.w;
        }
        const float* fr = &A[(size_t)grow * DIM + lane * 8];
        float4 f0 = *(const float4*)fr; float4 f1 = *(const float4*)(fr + 4);
        *(float4*)&out[(size_t)grow * DIM + lane * 8]     = make_float4(o[0], o[1], o[2], o[3]);
        *(float4*)&out[(size_t)grow * DIM + lane * 8 + 4] = make_float4(o[4], o[5], o[6], o[7]);
        lossAcc += fabsf(o[0]-f0.x) + fabsf(o[1]-f0.y) + fabsf(o[2]-f0.z) + fabsf(o[3]-f0.w)
                 + fabsf(o[4]-f1.x) + fabsf(o[5]-f1.y) + fabsf(o[6]-f1.z) + fabsf(o[7]-f1.w);
    }
#pragma unroll
    for (int off = 32; off; off >>= 1) lossAcc += __shfl_xor(lossAcc, off, 64);
    if (lane == 0) atomicAdd(&out[LOSS_OFF], lossAcc * (1.0f / ((float)NROWS * (float)DIM)));
}

extern "C" void kernel_launch(void* const* d_in, const int* in_sizes, int n_in,
                              void* d_out, int out_size, void* d_ws, size_t ws_size,
                              hipStream_t stream)
{
    const float* A  = (const float*)d_in[0];
    const float* Pr = (const float*)d_in[1];
    const float* U  = (const float*)d_in[2];
    float* out = (float*)d_out;

    const size_t szA = (size_t)NROWS * DIM;      // bytes per A limb plane
    const size_t szP = (size_t)NPROTO * DIM;     // bytes per P limb plane
    const size_t listBytes = (size_t)NROWS * LCAP * sizeof(uint2);
    const size_t need = 2 * szA + 2 * szP + (NROWS + NPROTO) * sizeof(float) + listBytes;

    zero_loss_kernel<<<1, 1, 0, stream>>>(out);

    if (ws_size >= need) {
        char*  wsA1 = (char*)d_ws;
        char*  wsA0 = wsA1 + szA;
        char*  wsP1 = wsA0 + szA;
        char*  wsP0 = wsP1 + szP;
        float* wsSA = (float*)(wsP0 + szP);
        float* wsSP = wsSA + NROWS;
        uint2* gList = (uint2*)((char*)(wsSP + NPROTO));
        split_i8_kernel<<<NROWS / 32, 256, 0, stream>>>(A, wsA1, wsA0, wsSA, NROWS);
        split_i8_kernel<<<NPROTO / 32, 256, 0, stream>>>(Pr, wsP1, wsP0, wsSP, NPROTO);
        attr_proto_wa2<<<NROWS / BM, 256, 0, stream>>>(A, Pr, U, out, gList,
                                                       wsA1, wsA0, wsP1, wsP0, wsSA, wsSP);
    } else {
        attr_proto_fused_valu<<<NROWS / 64, 256, 0, stream>>>(A, Pr, U, out);
    }
}